// Round 4
// baseline (29790.897 us; speedup 1.0000x reference)
//
#include <hip/hip_runtime.h>

// MUCMA sequential scan, single wave — round 4: zero LDS-pipe ops.
//
// Layout: lane = sl + 32*h, sl = lane&31, h = dim. Active row per half: sl 0..15.
//   sl 0..9  : taps. Lane holds frame elements 4sl..4sl+3 (lane 9: 34..37, A-part
//              masked) as v2f pairs (A = first 2, B = last 2), w likewise.
//   sl 10..15: r/z state, d = sl-10. Half h tracks r[h,1-h,d], z[d][1-h].
// Reduces: 4-stage row_ror butterfly -> row total broadcast to ALL 16 row lanes
// (v and the mu-sum arrive pre-broadcast at every consumer; c' computed redundantly
// per-lane; no bperm/readlane anywhere). Cross-half v (z-insert only) via one
// v_permlane32_swap_b32, direction self-calibrated at startup.

typedef float v2f __attribute__((ext_vector_type(2)));
typedef float v4f __attribute__((ext_vector_type(4), aligned(4)));

constexpr int   NTAPS  = 19;
constexpr int   FRST   = 38;                  // floats per frame (taps*dims)
constexpr float BETA_C = 0.999f;
constexpr float OMB_C  = 0.001f;              // float32(1 - 0.999) as the reference rounds
constexpr float LR_C   = 0.0001220703125f;    // 2^-13
constexpr float R2_C   = 1.32f;

template <int CTRL>
__device__ __forceinline__ float dpp_add(float x) {
    return x + __int_as_float(__builtin_amdgcn_update_dpp(
        0, __float_as_int(x), CTRL, 0xF, 0xF, true));
}
template <int CTRL>
__device__ __forceinline__ float dpp_mov(float x) {
    return __int_as_float(__builtin_amdgcn_update_dpp(
        0, __float_as_int(x), CTRL, 0xF, 0xF, true));
}
// 4-stage rotation butterfly within each 16-lane row: EVERY lane gets the row total.
__device__ __forceinline__ float rowred_bcast(float x) {
    x = dpp_add<0x121>(x);   // row_ror:1
    x = dpp_add<0x122>(x);   // row_ror:2
    x = dpp_add<0x124>(x);   // row_ror:4
    x = dpp_add<0x128>(x);   // row_ror:8
    return x;
}
// Swap data between the two 32-lane halves of two VGPRs (exact half-mapping
// calibrated at runtime). s_nop padding covers VALU<->permlane wait-states.
__device__ __forceinline__ void plane32_swap(float& a, float& b) {
    asm("s_nop 1\n\t"
        "v_permlane32_swap_b32 %0, %1\n\t"
        "s_nop 1"
        : "+v"(a), "+v"(b));
}

__global__ void __launch_bounds__(64, 1)
mucma_scan_kernel(const float* __restrict__ fr_re, const float* __restrict__ fr_im,
                  const float* __restrict__ w0r_in, const float* __restrict__ w0i_in,
                  float* __restrict__ out, int nsym)
{
    const int  lane = threadIdx.x;
    const int  sl   = lane & 31;
    const int  h    = lane >> 5;                         // this half's output dim
    const int  loff = (4 * sl < 34) ? 4 * sl : 34;       // float offset into frame (always in-bounds)
    const float mA  = (sl <= 8) ? 1.f : 0.f;             // element-ownership masks
    const float mB  = (sl <= 9) ? 1.f : 0.f;
    const bool d0f  = (sl == 10);                        // z-insert lane (d = 0)
    const bool stf  = (sl == 0);                         // store lane per half

    // ---- weights: lane sl<=8 owns elements 4sl..4sl+3; lane 9 owns 36,37 (B only) ----
    v2f wA_r = {0.f,0.f}, wA_i = {0.f,0.f}, wB_r = {0.f,0.f}, wB_i = {0.f,0.f};
    if (sl <= 8) {
        const int b = h * FRST + 2 * sl;
        wA_r.x = w0r_in[b];         wA_r.y = w0r_in[b + NTAPS];
        wA_i.x = w0i_in[b];         wA_i.y = w0i_in[b + NTAPS];
        wB_r.x = w0r_in[b + 1];     wB_r.y = w0r_in[b + NTAPS + 1];
        wB_i.x = w0i_in[b + 1];     wB_i.y = w0i_in[b + NTAPS + 1];
    } else if (sl == 9) {
        wB_r.x = w0r_in[h * FRST + 18];  wB_r.y = w0r_in[h * FRST + 37];
        wB_i.x = w0i_in[h * FRST + 18];  wB_i.y = w0i_in[h * FRST + 37];
    }
    float r_re = 0.f, r_im = 0.f, z_re = 0.f, z_im = 0.f;
    float bp = BETA_C;

    // ---- calibrate permlane32_swap half-mapping (robust to any half-exchange variant):
    // after {X=copy(V); swap(X,V)}, "cross" = (X != own) ? X : V per lane. ----
    bool csel;
    {
        const float own = h ? 11.f : 7.f;
        float v = own, X = own;
        plane32_swap(X, v);
        csel = (X != own);
    }

    const float* pre = fr_re + loff;
    const float* pim = fr_im + loff;

    // 8-deep register ring of 16B u-slices (slot = n & 7)
    v4f rr[8], ri[8];
#pragma unroll
    for (int p = 0; p < 8; ++p) {
        const int idx = (p < nsym) ? p : (nsym - 1);
        rr[p] = *(const v4f*)(pre + (size_t)idx * FRST);
        ri[p] = *(const v4f*)(pim + (size_t)idx * FRST);
    }

    auto body = [&](int n, int p, int npf) {
        const v4f uR = rr[p], uI = ri[p];
        rr[p] = *(const v4f*)(pre + (size_t)npf * FRST);   // refill: ~8 steps in flight
        ri[p] = *(const v4f*)(pim + (size_t)npf * FRST);

        const v2f uA_r = {uR.x, uR.y}, uB_r = {uR.z, uR.w};
        const v2f uA_i = {uI.x, uI.y}, uB_i = {uI.z, uI.w};

        // ---- v = <w,u>: packed complex products, pair-sum, row-broadcast reduce ----
        v2f tr = wA_r * uA_r - wA_i * uA_i + wB_r * uB_r - wB_i * uB_i;
        v2f ti = wA_r * uA_i + wA_i * uA_r + wB_r * uB_i + wB_i * uB_r;
        float xr = tr.x + tr.y;
        float xi = ti.x + ti.y;
        xr = rowred_bcast(xr);            // own-half v, broadcast to all row lanes
        xi = rowred_bcast(xi);
        const float vkr = xr, vki = xi;   // keep own v (swap clobbers xr/xi)

        // ---- cross-half v (other dim), one permlane swap per component ----
        float Xr = xr, Xi = xi;
        plane32_swap(Xr, xr);
        plane32_swap(Xi, xi);
        const float vlr = csel ? Xr : xr;
        const float vli = csel ? Xi : xi;

        // ---- z shift; insert v_l at d=0 ----
        const float zsr = dpp_mov<0x111>(z_re);
        const float zsi = dpp_mov<0x111>(z_im);
        z_re = d0f ? vlr : zsr;
        z_im = d0f ? vli : zsi;

        // ---- r = beta*r + (1-beta)*v_k*conj(z) (nonzero only on r-lanes; z=0 elsewhere) ----
        const float ar = OMB_C * vkr, ai = OMB_C * vki;
        r_re = BETA_C * r_re + (ar * z_re + ai * z_im);
        r_im = BETA_C * r_im + (ai * z_re - ar * z_im);

        // ---- mu partials + row-broadcast sum (zero outside r-lanes naturally) ----
        float qr = r_re * z_re + r_im * z_im;
        float qi = r_im * z_re - r_re * z_im;
        qr = rowred_bcast(qr);
        qi = rowred_bcast(qi);

        // ---- bias correction + c' (computed redundantly at every row lane) ----
        const float inv = __builtin_amdgcn_rcpf(1.0f - bp);
        bp *= BETA_C;
        const float i2 = (2.0f * LR_C) * inv;
        const float ek = R2_C - (vkr * vkr + vki * vki);
        const float e2 = (-2.0f * LR_C) * ek;
        const float cr = e2 * vkr + i2 * qr;
        const float ci = e2 * vki + i2 * qi;

        // ---- w -= c'*conj(u), element-ownership masked ----
        const float crA = cr * mA, ciA = ci * mA;
        const float crB = cr * mB, ciB = ci * mB;
        const v2f cAr = {crA, crA}, cAi = {ciA, ciA};
        const v2f cBr = {crB, crB}, cBi = {ciB, ciB};
        wA_r -= cAr * uA_r + cAi * uA_i;
        wA_i -= cAi * uA_r - cAr * uA_i;
        wB_r -= cBr * uB_r + cBi * uB_i;
        wB_i -= cBi * uB_r - cBr * uB_i;

        // ---- emit v(n): lanes 0 / 32 store their dim's (re,im) pair ----
        if (stf) {
            v2f o; o.x = vkr; o.y = vki;
            *(v2f*)(out + 4 * (size_t)n + 2 * h) = o;
        }
    };

    int NBmain = nsym / 8 - 1;               // blocks with unclamped prefetch
    if (NBmain < 0) NBmain = 0;
    for (int b = 0; b < NBmain; ++b) {
        const int nb = b * 8;
#pragma unroll
        for (int p = 0; p < 8; ++p) body(nb + p, p, nb + p + 8);
    }
    for (int nb = NBmain * 8; nb < nsym; nb += 8) {   // drain: clamped prefetch
#pragma unroll
        for (int p = 0; p < 8; ++p) {
            const int n = nb + p;
            if (n < nsym) {
                int npf = n + 8;
                if (npf > nsym - 1) npf = nsym - 1;
                body(n, p, npf);
            }
        }
    }
}

extern "C" void kernel_launch(void* const* d_in, const int* in_sizes, int n_in,
                              void* d_out, int out_size, void* d_ws, size_t ws_size,
                              hipStream_t stream)
{
    const float* fr_re = (const float*)d_in[0];
    const float* fr_im = (const float*)d_in[1];
    const float* w0r   = (const float*)d_in[2];
    const float* w0i   = (const float*)d_in[3];
    float* outp = (float*)d_out;
    const int nsym = in_sizes[0] / FRST;
    hipLaunchKernelGGL(mucma_scan_kernel, dim3(1), dim3(64), 0, stream,
                       fr_re, fr_im, w0r, w0i, outp, nsym);
}

// Round 5
// 29658.029 us; speedup vs baseline: 1.0045x; 1.0045x over previous
//
#include <hip/hip_runtime.h>

// MUCMA sequential scan — round 5: lag-1 lookahead with precomputed frame
// cross-correlations S(n) = <conj u(n), u(n+1)> (gram_kernel, fully parallel,
// written to d_ws). Scan identity:
//   v(n) = <w(n),u(n)> = <w(n-1),u(n)> - c'(n-1)*S(n-1) = A(n) - c'(n-1)*S(n-1)
// so the products+reduce tree for A(n+1) is INDEPENDENT of step n's scalar
// chain and fills its latency bubbles; the serial chain is only
// v-correction -> z/r/q -> c' (~80 cyc) vs ~170 cyc of issue.
//
// Lane layout (as round 4): lane = sl + 32*h, h = dim. Active: sl 0..15.
//   sl 0..9 : taps, 4 frame elements each (lane 9: elements 36,37 only).
//   sl 10..15: r/z state, d = sl-10.
// Loop split at SPLIT_N: beyond it 1-beta^(n+1) == 1.0f exactly -> drop rcp/bp.

typedef float v2f __attribute__((ext_vector_type(2)));
typedef float v4f __attribute__((ext_vector_type(4), aligned(8)));

constexpr int   NTAPS   = 19;
constexpr int   FRST    = 38;                  // floats per frame (taps*dims)
constexpr float BETA_C  = 0.999f;
constexpr float OMB_C   = 0.001f;              // float32(1 - 0.999)
constexpr float LR_C    = 0.0001220703125f;    // 2^-13
constexpr float R2_C    = 1.32f;
constexpr int   SPLIT_N = 24576;               // beta^(n+1) < 2^-25 for n >= this

template <int CTRL>
__device__ __forceinline__ float dpp_add(float x) {
    return x + __int_as_float(__builtin_amdgcn_update_dpp(
        0, __float_as_int(x), CTRL, 0xF, 0xF, true));
}
template <int CTRL>
__device__ __forceinline__ float dpp_mov(float x) {
    return __int_as_float(__builtin_amdgcn_update_dpp(
        0, __float_as_int(x), CTRL, 0xF, 0xF, true));
}
// 4-stage rotation butterfly in each 16-lane row: every lane gets the row total.
__device__ __forceinline__ float rowred_bcast(float x) {
    x = dpp_add<0x121>(x);   // row_ror:1
    x = dpp_add<0x122>(x);   // row_ror:2
    x = dpp_add<0x124>(x);   // row_ror:4
    x = dpp_add<0x128>(x);   // row_ror:8
    return x;
}
__device__ __forceinline__ void plane32_swap(float& a, float& b) {
    asm("s_nop 1\n\t"
        "v_permlane32_swap_b32 %0, %1\n\t"
        "s_nop 1"
        : "+v"(a), "+v"(b));
}
// Two swaps sharing one hazard window (saves 2 s_nop per step).
__device__ __forceinline__ void plane32_swap2(float& a, float& b, float& c, float& d) {
    asm("s_nop 1\n\t"
        "v_permlane32_swap_b32 %0, %1\n\t"
        "v_permlane32_swap_b32 %2, %3\n\t"
        "s_nop 1"
        : "+v"(a), "+v"(b), "+v"(c), "+v"(d));
}

// ---------- parallel precompute: S(n) = <conj u(n), u(n+1)>, n in [0, nsym) ----------
__global__ void __launch_bounds__(64)
gram_kernel(const float* __restrict__ fr_re, const float* __restrict__ fr_im,
            v2f* __restrict__ S, int nsym)
{
    __shared__ float lre[65 * FRST], lim[65 * FRST];
    const int lane = threadIdx.x;
    const int n0   = blockIdx.x * 64;
    const int gmax = nsym * FRST;
    for (int idx = lane; idx < 65 * FRST; idx += 64) {
        const int g = n0 * FRST + idx;
        if (g < gmax) { lre[idx] = fr_re[g]; lim[idx] = fr_im[g]; }
    }
    __syncthreads();
    const int n = n0 + lane;
    if (n >= nsym) return;
    v2f s = {0.f, 0.f};
    if (n + 1 < nsym) {
        const float* ar = lre + lane * FRST;
        const float* ai = lim + lane * FRST;
        const float* br = ar + FRST;
        const float* bi = ai + FRST;
#pragma unroll
        for (int e = 0; e < FRST; ++e) {
            s.x += ar[e] * br[e] + ai[e] * bi[e];   // re{conj(a)·b}
            s.y += ar[e] * bi[e] - ai[e] * br[e];   // im{conj(a)·b}
        }
    }
    S[n] = s;
}

// ---------- sequential scan ----------
struct LaneCtx {
    const float* pre; const float* pim; const v2f* Sb; float* out;
    float mA, mB; bool d0f, stf, csel; int h;
};
struct ScanSt {
    v2f  wA_r, wA_i, wB_r, wB_i;
    float r_re, r_im, z_re, z_im, bp;
    float Ar, Ai;          // A(n) = <w(n-1), u(n)>, broadcast in own half
    float cpr, cpi;        // c'(n-1), own half/dim
    v2f  sp;               // S(n-1), uniform
    v4f  rr[8], ri[8];     // u ring (slot = n & 7)
    v2f  sr[8];            // S ring
};

template <bool EARLY, int P>
__device__ __forceinline__ void mstep(int n, int npf, const LaneCtx& L, ScanSt& s)
{
    constexpr int PN = (P + 1) & 7;
    const v4f uR  = s.rr[P],  uI  = s.ri[P];     // u(n)
    const v4f u1R = s.rr[PN], u1I = s.ri[PN];    // u(n+1)
    s.rr[P] = *(const v4f*)(L.pre + (size_t)npf * FRST);
    s.ri[P] = *(const v4f*)(L.pim + (size_t)npf * FRST);
    const v2f Scur = s.sr[P];                    // S(n)
    s.sr[P] = L.Sb[npf];

    // ---- A(n+1) = <w(n), u(n+1)> : off-chain tree (reads w before update) ----
    const v2f uA_r = {u1R.x, u1R.y}, uB_r = {u1R.z, u1R.w};
    const v2f uA_i = {u1I.x, u1I.y}, uB_i = {u1I.z, u1I.w};
    v2f tr = s.wA_r * uA_r - s.wA_i * uA_i + s.wB_r * uB_r - s.wB_i * uB_i;
    v2f ti = s.wA_r * uA_i + s.wA_i * uA_r + s.wB_r * uB_i + s.wB_i * uB_r;
    float nAr = tr.x + tr.y;
    float nAi = ti.x + ti.y;
    nAr = rowred_bcast(nAr);
    nAi = rowred_bcast(nAi);

    // ---- v(n) = A(n) - c'(n-1)*S(n-1)  (own dim; all lanes; chain head) ----
    const float vkr = s.Ar - (s.cpr * s.sp.x - s.cpi * s.sp.y);
    const float vki = s.Ai - (s.cpr * s.sp.y + s.cpi * s.sp.x);

    if (L.stf) {                                 // emit v(n)
        v2f o; o.x = vkr; o.y = vki;
        *(v2f*)(L.out + 4 * (size_t)n + 2 * L.h) = o;
    }

    // ---- cross-half v for the z-insert ----
    float Xr = vkr, Yr = vkr, Xi = vki, Yi = vki;
    plane32_swap2(Xr, Yr, Xi, Yi);
    const float vlr = L.csel ? Xr : Yr;
    const float vli = L.csel ? Xi : Yi;

    // ---- z shift ----
    const float zsr = dpp_mov<0x111>(s.z_re);
    const float zsi = dpp_mov<0x111>(s.z_im);
    s.z_re = L.d0f ? vlr : zsr;
    s.z_im = L.d0f ? vli : zsi;

    // ---- r = beta*r + (1-beta)*v_k*conj(z) ----
    const float ar = OMB_C * vkr, ai = OMB_C * vki;
    s.r_re = BETA_C * s.r_re + (ar * s.z_re + ai * s.z_im);
    s.r_im = BETA_C * s.r_im + (ai * s.z_re - ar * s.z_im);

    // ---- mu partials + row-broadcast sum ----
    float qr = s.r_re * s.z_re + s.r_im * s.z_im;
    float qi = s.r_im * s.z_re - s.r_re * s.z_im;
    qr = rowred_bcast(qr);
    qi = rowred_bcast(qi);

    // ---- c' (redundant at every lane; i2 constant in late phase) ----
    float i2;
    if (EARLY) {
        const float inv = __builtin_amdgcn_rcpf(1.0f - s.bp);
        s.bp *= BETA_C;
        i2 = (2.0f * LR_C) * inv;
    } else {
        i2 = 2.0f * LR_C;
    }
    const float t  = vkr * vkr + vki * vki;
    const float e2 = fmaf(2.0f * LR_C, t, -(2.0f * LR_C) * R2_C); // -2LR*(R2-t)
    const float cr = fmaf(e2, vkr, i2 * qr);
    const float ci = fmaf(e2, vki, i2 * qi);

    // ---- w -= c'*conj(u(n)), ownership-masked ----
    const float crA = cr * L.mA, ciA = ci * L.mA;
    const float crB = cr * L.mB, ciB = ci * L.mB;
    const v2f uA_r0 = {uR.x, uR.y}, uB_r0 = {uR.z, uR.w};
    const v2f uA_i0 = {uI.x, uI.y}, uB_i0 = {uI.z, uI.w};
    const v2f cAr = {crA, crA}, cAi = {ciA, ciA};
    const v2f cBr = {crB, crB}, cBi = {ciB, ciB};
    s.wA_r -= cAr * uA_r0 + cAi * uA_i0;
    s.wA_i -= cAi * uA_r0 - cAr * uA_i0;
    s.wB_r -= cBr * uB_r0 + cBi * uB_i0;
    s.wB_i -= cBi * uB_r0 - cBr * uB_i0;

    // ---- rotate lookahead state ----
    s.Ar = nAr; s.Ai = nAi; s.cpr = cr; s.cpi = ci; s.sp = Scur;
}

template <bool EARLY>
__device__ __forceinline__ void block8(int nb, const LaneCtx& L, ScanSt& s) {
    mstep<EARLY, 0>(nb + 0, nb + 8,  L, s);
    mstep<EARLY, 1>(nb + 1, nb + 9,  L, s);
    mstep<EARLY, 2>(nb + 2, nb + 10, L, s);
    mstep<EARLY, 3>(nb + 3, nb + 11, L, s);
    mstep<EARLY, 4>(nb + 4, nb + 12, L, s);
    mstep<EARLY, 5>(nb + 5, nb + 13, L, s);
    mstep<EARLY, 6>(nb + 6, nb + 14, L, s);
    mstep<EARLY, 7>(nb + 7, nb + 15, L, s);
}
template <bool EARLY>
__device__ __forceinline__ void block8c(int nb, int nsym, const LaneCtx& L, ScanSt& s) {
    const int last = nsym - 1;
#define STEPC(K) { const int n = nb + K; if (n < nsym) { \
        int npf = n + 8; if (npf > last) npf = last; mstep<EARLY, K>(n, npf, L, s); } }
    STEPC(0) STEPC(1) STEPC(2) STEPC(3) STEPC(4) STEPC(5) STEPC(6) STEPC(7)
#undef STEPC
}

__global__ void __launch_bounds__(64, 1)
mucma_scan_kernel(const float* __restrict__ fr_re, const float* __restrict__ fr_im,
                  const float* __restrict__ w0r_in, const float* __restrict__ w0i_in,
                  const v2f* __restrict__ Sbuf, float* __restrict__ out, int nsym)
{
    const int lane = threadIdx.x;
    const int sl   = lane & 31;
    const int h    = lane >> 5;
    const int loff = (4 * sl < 34) ? 4 * sl : 34;

    LaneCtx L;
    L.pre = fr_re + loff;  L.pim = fr_im + loff;  L.Sb = Sbuf;  L.out = out;
    L.mA  = (sl <= 8) ? 1.f : 0.f;
    L.mB  = (sl <= 9) ? 1.f : 0.f;
    L.d0f = (sl == 10);
    L.stf = (sl == 0);
    L.h   = h;
    {   // calibrate permlane32_swap half-mapping
        const float own = h ? 11.f : 7.f;
        float v = own, X = own;
        plane32_swap(X, v);
        L.csel = (X != own);
    }

    ScanSt s;
    s.wA_r = {0.f,0.f}; s.wA_i = {0.f,0.f}; s.wB_r = {0.f,0.f}; s.wB_i = {0.f,0.f};
    if (sl <= 8) {
        const int b = h * FRST + 2 * sl;
        s.wA_r.x = w0r_in[b];       s.wA_r.y = w0r_in[b + NTAPS];
        s.wA_i.x = w0i_in[b];       s.wA_i.y = w0i_in[b + NTAPS];
        s.wB_r.x = w0r_in[b + 1];   s.wB_r.y = w0r_in[b + NTAPS + 1];
        s.wB_i.x = w0i_in[b + 1];   s.wB_i.y = w0i_in[b + NTAPS + 1];
    } else if (sl == 9) {
        s.wB_r.x = w0r_in[h * FRST + 18];  s.wB_r.y = w0r_in[h * FRST + 37];
        s.wB_i.x = w0i_in[h * FRST + 18];  s.wB_i.y = w0i_in[h * FRST + 37];
    }
    s.r_re = 0.f; s.r_im = 0.f; s.z_re = 0.f; s.z_im = 0.f;
    s.bp = BETA_C;
    s.cpr = 0.f; s.cpi = 0.f; s.sp = {0.f, 0.f};

#pragma unroll
    for (int p = 0; p < 8; ++p) {
        const int idx = (p < nsym) ? p : (nsym - 1);
        s.rr[p] = *(const v4f*)(L.pre + (size_t)idx * FRST);
        s.ri[p] = *(const v4f*)(L.pim + (size_t)idx * FRST);
        s.sr[p] = Sbuf[idx];
    }
    {   // prologue: A(0) = <w(0), u(0)>
        const v4f uR = s.rr[0], uI = s.ri[0];
        const v2f uA_r = {uR.x, uR.y}, uB_r = {uR.z, uR.w};
        const v2f uA_i = {uI.x, uI.y}, uB_i = {uI.z, uI.w};
        v2f tr = s.wA_r * uA_r - s.wA_i * uA_i + s.wB_r * uB_r - s.wB_i * uB_i;
        v2f ti = s.wA_r * uA_i + s.wA_i * uA_r + s.wB_r * uB_i + s.wB_i * uB_r;
        s.Ar = rowred_bcast(tr.x + tr.y);
        s.Ai = rowred_bcast(ti.x + ti.y);
    }

    if (nsym >= SPLIT_N + 16) {
        for (int nb = 0; nb < SPLIT_N; nb += 8)               // early: rcp/bp live
            block8<true>(nb, L, s);
        const int nmain = (nsym - 8) & ~7;                    // late, unclamped prefetch
        for (int nb = SPLIT_N; nb < nmain; nb += 8)
            block8<false>(nb, L, s);
        for (int nb = nmain; nb < nsym; nb += 8)              // late drain
            block8c<false>(nb, nsym, L, s);
    } else {
        for (int nb = 0; nb < nsym; nb += 8)
            block8c<true>(nb, nsym, L, s);
    }
}

extern "C" void kernel_launch(void* const* d_in, const int* in_sizes, int n_in,
                              void* d_out, int out_size, void* d_ws, size_t ws_size,
                              hipStream_t stream)
{
    const float* fr_re = (const float*)d_in[0];
    const float* fr_im = (const float*)d_in[1];
    const float* w0r   = (const float*)d_in[2];
    const float* w0i   = (const float*)d_in[3];
    float* outp = (float*)d_out;
    v2f*   Sbuf = (v2f*)d_ws;                   // nsym * 8 bytes
    const int nsym = in_sizes[0] / FRST;

    hipLaunchKernelGGL(gram_kernel, dim3((nsym + 63) / 64), dim3(64), 0, stream,
                       fr_re, fr_im, Sbuf, nsym);
    hipLaunchKernelGGL(mucma_scan_kernel, dim3(1), dim3(64), 0, stream,
                       fr_re, fr_im, w0r, w0i, Sbuf, outp, nsym);
}

// Round 6
// 29435.349 us; speedup vs baseline: 1.0121x; 1.0076x over previous
//
#include <hip/hip_runtime.h>
#include <stdint.h>

// MUCMA — round 6: two-wave producer/consumer split.
//   wave A (chain): v(n) = Araw(n) - c'(n-1)S1(n-1) - c'(n-2)S2(n-2) - c'(n-3)S3(n-3);
//                   z/r/q/c' recurrence; writes c'(n) to LDS; stores v(n).
//   wave B (tree):  maintains w lagged; Araw(m+2) = <w(m-1), u(m+2)> -> LDS.
//   Sk(n) = <conj u(n), u(n+k)> precomputed in parallel (gram3_kernel -> d_ws).
// Sync: one raw {lgkmcnt(0); s_barrier} per step — vmcnt NOT drained, so global
// prefetch rings survive barriers. Fallback (small ws / small n): round-4 kernel.

typedef float v2f __attribute__((ext_vector_type(2)));
typedef float v4f __attribute__((ext_vector_type(4), aligned(8)));

constexpr int   NTAPS   = 19;
constexpr int   FRST    = 38;
constexpr float BETA_C  = 0.999f;
constexpr float OMB_C   = 0.001f;
constexpr float LR_C    = 0.0001220703125f;   // 2^-13
constexpr float R2_C    = 1.32f;
constexpr int   SPLIT_N = 24576;              // beta^(n+1) == 0 in f32 beyond here

template <int CTRL>
__device__ __forceinline__ float dpp_add(float x) {
    return x + __int_as_float(__builtin_amdgcn_update_dpp(
        0, __float_as_int(x), CTRL, 0xF, 0xF, true));
}
template <int CTRL>
__device__ __forceinline__ float dpp_mov(float x) {
    return __int_as_float(__builtin_amdgcn_update_dpp(
        0, __float_as_int(x), CTRL, 0xF, 0xF, true));
}
// 4-stage rotation butterfly: every lane of each 16-lane row gets the row total.
__device__ __forceinline__ float rowred_bcast(float x) {
    x = dpp_add<0x121>(x);
    x = dpp_add<0x122>(x);
    x = dpp_add<0x124>(x);
    x = dpp_add<0x128>(x);
    return x;
}
__device__ __forceinline__ void plane32_swap(float& a, float& b) {
    asm("s_nop 1\n\t"
        "v_permlane32_swap_b32 %0, %1\n\t"
        "s_nop 1"
        : "+v"(a), "+v"(b));
}
__device__ __forceinline__ void plane32_swap2(float& a, float& b, float& c, float& d) {
    asm("s_nop 1\n\t"
        "v_permlane32_swap_b32 %0, %1\n\t"
        "v_permlane32_swap_b32 %2, %3\n\t"
        "s_nop 1"
        : "+v"(a), "+v"(b), "+v"(c), "+v"(d));
}
__device__ __forceinline__ void wg_barrier() {
    asm volatile("s_waitcnt lgkmcnt(0)\n\ts_barrier" ::: "memory");
}

// ---------- parallel precompute: Sk(n) = <conj u(n), u(n+k)>, k=1..3 ----------
__global__ void __launch_bounds__(64)
gram3_kernel(const float* __restrict__ fr_re, const float* __restrict__ fr_im,
             char* __restrict__ ws, int nsym)
{
    v4f* SA4 = (v4f*)ws;                              // {S1r,S1i,S2r,S2i}
    v2f* SA2 = (v2f*)(ws + (size_t)nsym * 16);        // {S3r,S3i}
    __shared__ float lre[67 * FRST], lim[67 * FRST];
    const int lane = threadIdx.x;
    const int n0   = blockIdx.x * 64;
    const long gmax = (long)nsym * FRST;
    for (int idx = lane; idx < 67 * FRST; idx += 64) {
        const long g = (long)n0 * FRST + idx;
        if (g < gmax) { lre[idx] = fr_re[g]; lim[idx] = fr_im[g]; }
    }
    __syncthreads();
    const int n = n0 + lane;
    if (n >= nsym) return;
    const float* ar = lre + lane * FRST;
    const float* ai = lim + lane * FRST;
    v2f s1 = {0.f,0.f}, s2 = {0.f,0.f}, s3 = {0.f,0.f};
#pragma unroll
    for (int e = 0; e < FRST; ++e) {
        const float xr = ar[e], xi = ai[e];
        const float b1r = ar[e+FRST],   b1i = ai[e+FRST];
        const float b2r = ar[e+2*FRST], b2i = ai[e+2*FRST];
        const float b3r = ar[e+3*FRST], b3i = ai[e+3*FRST];
        s1.x += xr*b1r + xi*b1i;  s1.y += xr*b1i - xi*b1r;
        s2.x += xr*b2r + xi*b2i;  s2.y += xr*b2i - xi*b2r;
        s3.x += xr*b3r + xi*b3i;  s3.y += xr*b3i - xi*b3r;
    }
    if (n + 1 >= nsym) s1 = (v2f){0.f,0.f};
    if (n + 2 >= nsym) s2 = (v2f){0.f,0.f};
    if (n + 3 >= nsym) s3 = (v2f){0.f,0.f};
    SA4[n] = (v4f){s1.x, s1.y, s2.x, s2.y};
    SA2[n] = s3;
}

// ---------- wave A state / step ----------
struct AS {
    float araw_r, araw_i;
    float cp1r, cp1i, cp2r, cp2i, cp3r, cp3i;
    float z_re, z_im, r_re, r_im, bp;
    v4f sa4[8]; v2f sa2[8];
    const v4f* pa40; const v2f* pa20;   // bases (for tail clamping)
    const v4f* pa4;  const v2f* pa2;    // advancing per-block bases
    float* stb; int stadv;
};

template <bool EARLY, int P>
__device__ __forceinline__ void A_step(AS& s, const v4f* p4, const v2f* p2,
                                       float* sp, float* cw, const float* ard,
                                       bool d0f, bool csel)
{
    const v4f S1e = s.sa4[(P+7)&7];
    const v4f S2e = s.sa4[(P+6)&7];
    const v2f S3e = s.sa2[(P+5)&7];

    float vr = s.araw_r - (s.cp1r*S1e.x - s.cp1i*S1e.y)
                        - (s.cp2r*S2e.z - s.cp2i*S2e.w)
                        - (s.cp3r*S3e.x - s.cp3i*S3e.y);
    float vi = s.araw_i - (s.cp1r*S1e.y + s.cp1i*S1e.x)
                        - (s.cp2r*S2e.w + s.cp2i*S2e.z)
                        - (s.cp3r*S3e.y + s.cp3i*S3e.x);

    const v2f an = *(const v2f*)(ard + ((P+1)&7)*4);   // prefetch Araw(n+1)

    *(v2f*)sp = (v2f){vr, vi};                          // emit v(n)

    float Xr = vr, Yr = vr, Xi = vi, Yi = vi;
    plane32_swap2(Xr, Yr, Xi, Yi);
    const float vlr = csel ? Xr : Yr;
    const float vli = csel ? Xi : Yi;

    const float zsr = dpp_mov<0x111>(s.z_re);
    const float zsi = dpp_mov<0x111>(s.z_im);
    s.z_re = d0f ? vlr : zsr;
    s.z_im = d0f ? vli : zsi;

    const float ar = OMB_C * vr, ai = OMB_C * vi;
    s.r_re = BETA_C * s.r_re + (ar * s.z_re + ai * s.z_im);
    s.r_im = BETA_C * s.r_im + (ai * s.z_re - ar * s.z_im);

    float qr = s.r_re * s.z_re + s.r_im * s.z_im;
    float qi = s.r_im * s.z_re - s.r_re * s.z_im;
    qr = rowred_bcast(qr);
    qi = rowred_bcast(qi);

    float i2;
    if (EARLY) {
        const float inv = __builtin_amdgcn_rcpf(1.0f - s.bp);
        s.bp *= BETA_C;
        i2 = (2.0f * LR_C) * inv;
    } else {
        i2 = 2.0f * LR_C;
    }
    const float t  = vr*vr + vi*vi;
    const float e2 = fmaf(2.0f*LR_C, t, -(2.0f*LR_C)*R2_C);
    const float cr = fmaf(e2, vr, i2*qr);
    const float ci = fmaf(e2, vi, i2*qi);

    *(v2f*)(cw + P*4) = (v2f){cr, ci};                  // publish c'(n)

    s.cp3r = s.cp2r; s.cp3i = s.cp2i;
    s.cp2r = s.cp1r; s.cp2i = s.cp1i;
    s.cp1r = cr;     s.cp1i = ci;
    s.araw_r = an.x; s.araw_i = an.y;

    s.sa4[(P+5)&7] = p4[0];                             // S-ring refill
    s.sa2[(P+5)&7] = p2[0];
}

template <bool EARLY, bool TAIL>
__device__ __forceinline__ void a_block(AS& s, int nb, int last,
    float* cw, const float* ard, bool d0f, bool csel, float* gdl)
{
#define ASTP(P) { \
    const v4f* p4; const v2f* p2; float* sp; \
    if (TAIL) { int rfi = nb + P + 5; if (rfi > last) rfi = last; \
                p4 = s.pa40 + rfi; p2 = s.pa20 + rfi; \
                sp = (nb + P <= last) ? (s.stb + P*4) : (gdl + P*4); } \
    else { p4 = s.pa4 + (P+5); p2 = s.pa2 + (P+5); sp = s.stb + P*4; } \
    A_step<EARLY, P>(s, p4, p2, sp, cw, ard, d0f, csel); \
    wg_barrier(); }
    ASTP(0) ASTP(1) ASTP(2) ASTP(3) ASTP(4) ASTP(5) ASTP(6) ASTP(7)
#undef ASTP
    s.pa4 += 8; s.pa2 += 8; s.stb += s.stadv;
}

// ---------- wave B state / step ----------
struct BS {
    v2f wA_r, wA_i, wB_r, wB_i;
    v4f rr[8], ri[8];
    v4f uo_r, uo_i;               // u(m-2)
    float cregr, cregi;           // c'(m-2)
    const float* ubr; const float* ubi;
    float mA, mB;
};

__device__ __forceinline__ v2f b_tree(const BS& s, const v4f& uR, const v4f& uI) {
    const v2f uA_r = {uR.x,uR.y}, uB_r = {uR.z,uR.w};
    const v2f uA_i = {uI.x,uI.y}, uB_i = {uI.z,uI.w};
    v2f tr = s.wA_r*uA_r - s.wA_i*uA_i + s.wB_r*uB_r - s.wB_i*uB_i;
    v2f ti = s.wA_r*uA_i + s.wA_i*uA_r + s.wB_r*uB_i + s.wB_i*uB_r;
    return (v2f){ rowred_bcast(tr.x + tr.y), rowred_bcast(ti.x + ti.y) };
}

template <int P>
__device__ __forceinline__ void B_step(BS& s, const float* urf_re, const float* urf_im,
                                       const float* crd, float* aw)
{
    const v2f cn = *(const v2f*)(crd + ((P+7)&7)*4);    // c'(m-1), for next iter

    // w(m-2) -> w(m-1) with c'(m-2), conj(u(m-2))
    const float crA = s.cregr * s.mA, ciA = s.cregi * s.mA;
    const float crB = s.cregr * s.mB, ciB = s.cregi * s.mB;
    {
        const v2f uA_r = {s.uo_r.x, s.uo_r.y}, uB_r = {s.uo_r.z, s.uo_r.w};
        const v2f uA_i = {s.uo_i.x, s.uo_i.y}, uB_i = {s.uo_i.z, s.uo_i.w};
        s.wA_r -= (v2f){crA,crA}*uA_r + (v2f){ciA,ciA}*uA_i;
        s.wA_i -= (v2f){ciA,ciA}*uA_r - (v2f){crA,crA}*uA_i;
        s.wB_r -= (v2f){crB,crB}*uB_r + (v2f){ciB,ciB}*uB_i;
        s.wB_i -= (v2f){ciB,ciB}*uB_r - (v2f){crB,crB}*uB_i;
    }
    // Araw(m+2) = <w(m-1), u(m+2)>
    {
        const v2f T = b_tree(s, s.rr[(P+2)&7], s.ri[(P+2)&7]);
        *(v2f*)(aw + ((P+2)&7)*4) = T;
    }
    s.uo_r = s.rr[(P+7)&7];
    s.uo_i = s.ri[(P+7)&7];
    s.rr[(P+7)&7] = *(const v4f*)urf_re;                // u(m+7) refill
    s.ri[(P+7)&7] = *(const v4f*)urf_im;
    s.cregr = cn.x; s.cregi = cn.y;
}

template <bool TAIL>
__device__ __forceinline__ void b_block(BS& s, int nb, int last,
    const float* fr_re, const float* fr_im, int loff,
    const float* crd, float* aw)
{
#define BSTP(P) { \
    const float* ur; const float* ui2; \
    if (TAIL) { int rfi = nb + P + 7; if (rfi > last) rfi = last; \
                ur  = fr_re + (size_t)rfi * FRST + loff; \
                ui2 = fr_im + (size_t)rfi * FRST + loff; } \
    else { ur = s.ubr + P*FRST; ui2 = s.ubi + P*FRST; } \
    B_step<P>(s, ur, ui2, crd, aw); \
    wg_barrier(); }
    BSTP(0) BSTP(1) BSTP(2) BSTP(3) BSTP(4) BSTP(5) BSTP(6) BSTP(7)
#undef BSTP
    s.ubr += 8*FRST; s.ubi += 8*FRST;
}

// ---------- 2-wave scan kernel ----------
__global__ void __launch_bounds__(128, 1)
mucma2_kernel(const float* __restrict__ fr_re, const float* __restrict__ fr_im,
              const float* __restrict__ w0r_in, const float* __restrict__ w0i_in,
              char* __restrict__ ws, float* __restrict__ out, int nsym)
{
    __shared__ __align__(16) float cring[8][2][2];
    __shared__ __align__(16) float aring[8][2][2];
    __shared__ __align__(16) float ldsd[2048];

    const int  tid  = threadIdx.x;
    const int  wid  = tid >> 6;
    const int  lane = tid & 63;
    const int  sl   = lane & 31;
    const int  h    = lane >> 5;
    const int  loff = (4*sl < 34) ? 4*sl : 34;
    const bool d0f  = (sl == 10);
    const bool stf  = (sl == 0);
    const int  last = nsym - 1;

    bool csel;
    { const float own = h ? 11.f : 7.f; float v = own, X = own;
      plane32_swap(X, v); csel = (X != own); }

    int NBm = (nsym - 14) / 8; if (NBm < 0) NBm = 0;
    const int nmain = NBm * 8;
    const int ne    = (SPLIT_N < nmain) ? SPLIT_N : nmain;

    if (wid == 0) {
        // ================= wave A (chain) =================
        if (lane < 32) ((float*)cring)[lane] = 0.f;
        else           ((float*)aring)[lane - 32] = 0.f;
        wg_barrier();                                   // #1
        wg_barrier();                                   // #2 (B wrote Araw(0),Araw(1))

        AS s;
        uintptr_t a4u = (uintptr_t)ws;                     asm volatile("" : "+v"(a4u));
        uintptr_t a2u = (uintptr_t)(ws + (size_t)nsym*16); asm volatile("" : "+v"(a2u));
        s.pa40 = (const v4f*)a4u; s.pa20 = (const v2f*)a2u;
        s.pa4 = s.pa40; s.pa2 = s.pa20;
#pragma unroll
        for (int k = 0; k < 8; ++k) {
            const int idx = (k < 5) ? ((k <= last) ? k : last) : 0;
            s.sa4[k] = s.pa40[idx];
            s.sa2[k] = s.pa20[idx];
        }
        float* gdum = (float*)(ws + (size_t)nsym*24);
        float* gdl  = gdum + lane*32;
        s.stb   = stf ? (out + 2*h) : gdl;
        s.stadv = stf ? 32 : 0;
        s.cp1r=0.f; s.cp1i=0.f; s.cp2r=0.f; s.cp2i=0.f; s.cp3r=0.f; s.cp3i=0.f;
        s.z_re=0.f; s.z_im=0.f; s.r_re=0.f; s.r_im=0.f; s.bp = BETA_C;
        { const v2f a0 = *(const v2f*)&aring[0][h][0]; s.araw_r = a0.x; s.araw_i = a0.y; }
        float* cw = stf ? &cring[0][h][0] : &ldsd[lane*32];
        const float* ard = &aring[0][h][0];

        for (int nb = 0;  nb < ne;    nb += 8) a_block<true , false>(s, nb, last, cw, ard, d0f, csel, gdl);
        for (int nb = ne; nb < nmain; nb += 8) a_block<false, false>(s, nb, last, cw, ard, d0f, csel, gdl);
        if (nmain < SPLIT_N)
            for (int nb = nmain; nb < nsym; nb += 8) a_block<true , true>(s, nb, last, cw, ard, d0f, csel, gdl);
        else
            for (int nb = nmain; nb < nsym; nb += 8) a_block<false, true>(s, nb, last, cw, ard, d0f, csel, gdl);
    } else {
        // ================= wave B (tree) =================
        BS s;
        s.mA = (sl <= 8) ? 1.f : 0.f;
        s.mB = (sl <= 9) ? 1.f : 0.f;
        s.wA_r = (v2f){0.f,0.f}; s.wA_i = (v2f){0.f,0.f};
        s.wB_r = (v2f){0.f,0.f}; s.wB_i = (v2f){0.f,0.f};
        if (sl <= 8) {
            const int b = h*FRST + 2*sl;
            s.wA_r.x = w0r_in[b];       s.wA_r.y = w0r_in[b+NTAPS];
            s.wA_i.x = w0i_in[b];       s.wA_i.y = w0i_in[b+NTAPS];
            s.wB_r.x = w0r_in[b+1];     s.wB_r.y = w0r_in[b+NTAPS+1];
            s.wB_i.x = w0i_in[b+1];     s.wB_i.y = w0i_in[b+NTAPS+1];
        } else if (sl == 9) {
            s.wB_r.x = w0r_in[h*FRST+18];  s.wB_r.y = w0r_in[h*FRST+37];
            s.wB_i.x = w0i_in[h*FRST+18];  s.wB_i.y = w0i_in[h*FRST+37];
        }
        const float* pre = fr_re + loff;
        const float* pim = fr_im + loff;
#pragma unroll
        for (int k = 0; k < 7; ++k) {
            const int idx = (k <= last) ? k : last;
            s.rr[k] = *(const v4f*)(pre + (size_t)idx*FRST);
            s.ri[k] = *(const v4f*)(pim + (size_t)idx*FRST);
        }
        s.rr[7] = (v4f){0.f,0.f,0.f,0.f}; s.ri[7] = (v4f){0.f,0.f,0.f,0.f};
        s.uo_r  = (v4f){0.f,0.f,0.f,0.f}; s.uo_i  = (v4f){0.f,0.f,0.f,0.f};
        s.cregr = 0.f; s.cregi = 0.f;
        s.ubr = pre + (size_t)7*FRST;
        s.ubi = pim + (size_t)7*FRST;
        float* aw = stf ? &aring[0][h][0] : &ldsd[lane*32 + 2];
        const float* crd = &cring[0][h][0];

        wg_barrier();                                   // #1 (rings zeroed)
        {
            const v2f T0 = b_tree(s, s.rr[0], s.ri[0]);
            *(v2f*)(aw + 0) = T0;                       // Araw(0)
            const v2f T1 = b_tree(s, s.rr[1], s.ri[1]);
            *(v2f*)(aw + 4) = T1;                       // Araw(1)
        }
        wg_barrier();                                   // #2

        for (int nb = 0;     nb < nmain; nb += 8) b_block<false>(s, nb, last, fr_re, fr_im, loff, crd, aw);
        for (int nb = nmain; nb < nsym;  nb += 8) b_block<true >(s, nb, last, fr_re, fr_im, loff, crd, aw);
    }
}

// ---------- fallback: round-4 single-wave kernel (no workspace needed) ----------
__global__ void __launch_bounds__(64, 1)
mucma_scan_fb(const float* __restrict__ fr_re, const float* __restrict__ fr_im,
              const float* __restrict__ w0r_in, const float* __restrict__ w0i_in,
              float* __restrict__ out, int nsym)
{
    const int  lane = threadIdx.x;
    const int  sl   = lane & 31;
    const int  h    = lane >> 5;
    const int  loff = (4 * sl < 34) ? 4 * sl : 34;
    const float mA  = (sl <= 8) ? 1.f : 0.f;
    const float mB  = (sl <= 9) ? 1.f : 0.f;
    const bool d0f  = (sl == 10);
    const bool stfl = (sl == 0);

    v2f wA_r = {0.f,0.f}, wA_i = {0.f,0.f}, wB_r = {0.f,0.f}, wB_i = {0.f,0.f};
    if (sl <= 8) {
        const int b = h * FRST + 2 * sl;
        wA_r.x = w0r_in[b];         wA_r.y = w0r_in[b + NTAPS];
        wA_i.x = w0i_in[b];         wA_i.y = w0i_in[b + NTAPS];
        wB_r.x = w0r_in[b + 1];     wB_r.y = w0r_in[b + NTAPS + 1];
        wB_i.x = w0i_in[b + 1];     wB_i.y = w0i_in[b + NTAPS + 1];
    } else if (sl == 9) {
        wB_r.x = w0r_in[h * FRST + 18];  wB_r.y = w0r_in[h * FRST + 37];
        wB_i.x = w0i_in[h * FRST + 18];  wB_i.y = w0i_in[h * FRST + 37];
    }
    float r_re = 0.f, r_im = 0.f, z_re = 0.f, z_im = 0.f;
    float bp = BETA_C;

    bool csel;
    {
        const float own = h ? 11.f : 7.f;
        float v = own, X = own;
        plane32_swap(X, v);
        csel = (X != own);
    }

    const float* pre = fr_re + loff;
    const float* pim = fr_im + loff;

    v4f rr[8], ri[8];
#pragma unroll
    for (int p = 0; p < 8; ++p) {
        const int idx = (p < nsym) ? p : (nsym - 1);
        rr[p] = *(const v4f*)(pre + (size_t)idx * FRST);
        ri[p] = *(const v4f*)(pim + (size_t)idx * FRST);
    }

    auto body = [&](int n, int p, int npf) {
        const v4f uR = rr[p], uI = ri[p];
        rr[p] = *(const v4f*)(pre + (size_t)npf * FRST);
        ri[p] = *(const v4f*)(pim + (size_t)npf * FRST);

        const v2f uA_r = {uR.x, uR.y}, uB_r = {uR.z, uR.w};
        const v2f uA_i = {uI.x, uI.y}, uB_i = {uI.z, uI.w};

        v2f tr = wA_r * uA_r - wA_i * uA_i + wB_r * uB_r - wB_i * uB_i;
        v2f ti = wA_r * uA_i + wA_i * uA_r + wB_r * uB_i + wB_i * uB_r;
        float xr = rowred_bcast(tr.x + tr.y);
        float xi = rowred_bcast(ti.x + ti.y);
        const float vkr = xr, vki = xi;

        float Xr = xr, Xi = xi;
        plane32_swap(Xr, xr);
        plane32_swap(Xi, xi);
        const float vlr = csel ? Xr : xr;
        const float vli = csel ? Xi : xi;

        const float zsr = dpp_mov<0x111>(z_re);
        const float zsi = dpp_mov<0x111>(z_im);
        z_re = d0f ? vlr : zsr;
        z_im = d0f ? vli : zsi;

        const float ar = OMB_C * vkr, ai = OMB_C * vki;
        r_re = BETA_C * r_re + (ar * z_re + ai * z_im);
        r_im = BETA_C * r_im + (ai * z_re - ar * z_im);

        float qr = r_re * z_re + r_im * z_im;
        float qi = r_im * z_re - r_re * z_im;
        qr = rowred_bcast(qr);
        qi = rowred_bcast(qi);

        const float inv = __builtin_amdgcn_rcpf(1.0f - bp);
        bp *= BETA_C;
        const float i2 = (2.0f * LR_C) * inv;
        const float ek = R2_C - (vkr * vkr + vki * vki);
        const float e2 = (-2.0f * LR_C) * ek;
        const float cr = e2 * vkr + i2 * qr;
        const float ci = e2 * vki + i2 * qi;

        const float crA = cr * mA, ciA = ci * mA;
        const float crB = cr * mB, ciB = ci * mB;
        wA_r -= (v2f){crA,crA} * uA_r + (v2f){ciA,ciA} * uA_i;
        wA_i -= (v2f){ciA,ciA} * uA_r - (v2f){crA,crA} * uA_i;
        wB_r -= (v2f){crB,crB} * uB_r + (v2f){ciB,ciB} * uB_i;
        wB_i -= (v2f){ciB,ciB} * uB_r - (v2f){crB,crB} * uB_i;

        if (stfl) {
            v2f o; o.x = vkr; o.y = vki;
            *(v2f*)(out + 4 * (size_t)n + 2 * h) = o;
        }
    };

    int NBmain = nsym / 8 - 1;
    if (NBmain < 0) NBmain = 0;
    for (int b = 0; b < NBmain; ++b) {
        const int nb = b * 8;
#pragma unroll
        for (int p = 0; p < 8; ++p) body(nb + p, p, nb + p + 8);
    }
    for (int nb = NBmain * 8; nb < nsym; nb += 8) {
#pragma unroll
        for (int p = 0; p < 8; ++p) {
            const int n = nb + p;
            if (n < nsym) {
                int npf = n + 8;
                if (npf > nsym - 1) npf = nsym - 1;
                body(n, p, npf);
            }
        }
    }
}

extern "C" void kernel_launch(void* const* d_in, const int* in_sizes, int n_in,
                              void* d_out, int out_size, void* d_ws, size_t ws_size,
                              hipStream_t stream)
{
    const float* fr_re = (const float*)d_in[0];
    const float* fr_im = (const float*)d_in[1];
    const float* w0r   = (const float*)d_in[2];
    const float* w0i   = (const float*)d_in[3];
    float* outp = (float*)d_out;
    const int nsym = in_sizes[0] / FRST;

    const size_t need = (size_t)nsym * 24 + 64 * 1024;
    if (ws_size >= need && nsym >= 16) {
        hipLaunchKernelGGL(gram3_kernel, dim3((nsym + 63) / 64), dim3(64), 0, stream,
                           fr_re, fr_im, (char*)d_ws, nsym);
        hipLaunchKernelGGL(mucma2_kernel, dim3(1), dim3(128), 0, stream,
                           fr_re, fr_im, w0r, w0i, (char*)d_ws, outp, nsym);
    } else {
        hipLaunchKernelGGL(mucma_scan_fb, dim3(1), dim3(64), 0, stream,
                           fr_re, fr_im, w0r, w0i, outp, nsym);
    }
}